// Round 1
// baseline (2537.125 us; speedup 1.0000x reference)
//
#include <hip/hip_runtime.h>
#include <stdint.h>

// B = 1048576 rows, HID = 64. Residual MLP with training-mode BatchNorm.
// Strategy: bf16 activations (128 MB in d_ws), recompute-fused layer kernels:
//   each kernel re-does matmul_i (stats already known), applies BN+residual,
//   does matmul_{i+1} only to accumulate its stats (never stored).
// MFMA 16x16x32 bf16; layouts per verified gfx950 mappings:
//   A: row = lane&15, k = (lane>>4)*8 + j   (16B contiguous -> b128 / dwordx4)
//   B: col = lane&15, k = (lane>>4)*8 + j   (load from W^T, row-major)
//   C/D: col = lane&15, row = (lane>>4)*4 + reg

#define NROWS 1048576
#define EPS 1e-5f
#define INV_B 9.5367431640625e-07f  // 1/2^20 exact

typedef __attribute__((ext_vector_type(8))) short bfrag;   // 8 bf16 = 4 VGPR
typedef __attribute__((ext_vector_type(4))) float facc;    // MFMA C/D
typedef __attribute__((ext_vector_type(4))) float f4v;

__device__ __forceinline__ float bf2f(short s) {
  union { unsigned u; float f; } v;
  v.u = ((unsigned)(unsigned short)s) << 16;
  return v.f;
}
__device__ __forceinline__ short f2bf(float f) {
  union { float f; unsigned u; } v;
  v.f = f;
  unsigned r = v.u + 0x7FFFu + ((v.u >> 16) & 1u);  // RNE
  return (short)(r >> 16);
}
__device__ __forceinline__ float tanh_fast(float x) {
  float xc = fminf(fmaxf(x, -15.f), 15.f);
  float e = __expf(2.f * xc);
  return (e - 1.f) / (e + 1.f);
}

// ---------------- small kernels ----------------

// stats of x (4 cols): sum + sumsq -> sx[0..3], sx[4..7]
__global__ __launch_bounds__(256) void k_stats_x(const float* __restrict__ x,
                                                 float* __restrict__ sx) {
  int tid = threadIdx.x;
  size_t base = (size_t)blockIdx.x * 1024 + tid;
  float s[4] = {0.f, 0.f, 0.f, 0.f}, q[4] = {0.f, 0.f, 0.f, 0.f};
#pragma unroll
  for (int it = 0; it < 4; ++it) {
    f4v v = *(const f4v*)(x + (base + (size_t)it * 256) * 4);
#pragma unroll
    for (int k = 0; k < 4; ++k) { s[k] += v[k]; q[k] = fmaf(v[k], v[k], q[k]); }
  }
#pragma unroll
  for (int off = 32; off > 0; off >>= 1) {
#pragma unroll
    for (int k = 0; k < 4; ++k) {
      s[k] += __shfl_xor(s[k], off);
      q[k] += __shfl_xor(q[k], off);
    }
  }
  if ((tid & 63) == 0) {
#pragma unroll
    for (int k = 0; k < 4; ++k) {
      atomicAdd(&sx[k], s[k]);
      atomicAdd(&sx[4 + k], q[k]);
    }
  }
}

// stats of Z1 = tanh(bn0(x) @ W0 + b0): one wave handles 256 rows, lane = col
__global__ __launch_bounds__(256) void k_stats_z1(
    const float* __restrict__ x, const float* __restrict__ bn0g,
    const float* __restrict__ bn0b, const float* __restrict__ W0,
    const float* __restrict__ b0, const float* __restrict__ sx,
    float* __restrict__ s1) {
  int lane = threadIdx.x & 63;
  int gw = blockIdx.x * 4 + (threadIdx.x >> 6);
  float sc[4], sh[4];
#pragma unroll
  for (int k = 0; k < 4; ++k) {
    float mean = sx[k] * INV_B;
    float var = fmaf(-mean, mean, sx[4 + k] * INV_B);
    float rs = rsqrtf(var + EPS);
    sc[k] = bn0g[k] * rs;
    sh[k] = fmaf(-sc[k], mean, bn0b[k]);
  }
  float w[4];
#pragma unroll
  for (int k = 0; k < 4; ++k) w[k] = W0[k * 64 + lane];
  float bj = b0[lane];
  float s = 0.f, q = 0.f;
  size_t r0 = (size_t)gw * 256;
  for (int r = 0; r < 256; ++r) {
    f4v xv = *(const f4v*)(x + (r0 + r) * 4);
    float acc = bj;
#pragma unroll
    for (int k = 0; k < 4; ++k)
      acc = fmaf(fmaf(xv[k], sc[k], sh[k]), w[k], acc);
    float z = tanh_fast(acc);
    s += z;
    q = fmaf(z, z, q);
  }
  atomicAdd(&s1[lane], s);
  atomicAdd(&s1[64 + lane], q);
}

// transpose W_hid (4 x 64 x 64) -> bf16 W^T, WT[l][c][k]
__global__ __launch_bounds__(256) void k_prep(const float* __restrict__ Wh,
                                              short* __restrict__ WT) {
  int idx = blockIdx.x * 256 + threadIdx.x;  // 16384 total
  int l = idx >> 12, rem = idx & 4095, k = rem >> 6, c = rem & 63;
  WT[l * 4096 + c * 64 + k] = f2bf(Wh[l * 4096 + k * 64 + c]);
}

// ---------------- big fused kernels: 128 rows/block, 4 waves of 32 rows ----

// K_first: Y1 = BN(tanh(bn0(x)@W0+b0)) (no skip), write Y1 bf16,
// accumulate stats of Z2 = tanh(Y1 @ W_hid0 + b_hid0)
__global__ __launch_bounds__(256) void k_first(
    const float* __restrict__ x, const float* __restrict__ bn0g,
    const float* __restrict__ bn0b, const float* __restrict__ W0,
    const float* __restrict__ b0, const float* __restrict__ gamma0,
    const float* __restrict__ beta0, const float* __restrict__ sx,
    const float* __restrict__ s1, const short* __restrict__ WTb,
    const float* __restrict__ bb, float* __restrict__ s2,
    short* __restrict__ Y) {
  __shared__ __align__(16) float lds_x[128 * 4];
  __shared__ float lds_W0[256];
  __shared__ float lds_b0[64], lds_A1[64], lds_B1[64], lds_bb[64];
  __shared__ float lds_s0[4], lds_sh0[4];
  __shared__ __align__(16) short lds_y2[128 * 72];
  __shared__ float lds_st[128];

  const int tid = threadIdx.x;
  const int lane = tid & 63;
  const int wave = tid >> 6;
  const int l15 = lane & 15;
  const int q = lane >> 4;
  const size_t r0 = (size_t)blockIdx.x * 128;

  if (tid < 128) {
    *(f4v*)(lds_x + tid * 4) = *(const f4v*)(x + (r0 + tid) * 4);
    lds_st[tid] = 0.f;
  }
  lds_W0[tid] = W0[tid];
  if (tid < 64) {
    lds_b0[tid] = b0[tid];
    float mean = s1[tid] * INV_B;
    float var = fmaf(-mean, mean, s1[64 + tid] * INV_B);
    float rs = rsqrtf(var + EPS);
    float A = gamma0[tid] * rs;
    lds_A1[tid] = A;
    lds_B1[tid] = fmaf(-A, mean, beta0[tid]);
    lds_bb[tid] = bb[tid];
  }
  if (tid < 4) {
    float mean = sx[tid] * INV_B;
    float var = fmaf(-mean, mean, sx[4 + tid] * INV_B);
    float rs = rsqrtf(var + EPS);
    float sc = bn0g[tid] * rs;
    lds_s0[tid] = sc;
    lds_sh0[tid] = fmaf(-sc, mean, bn0b[tid]);
  }
  __syncthreads();

  // phase A: Y1 tile into lds_y2 (bf16, stride 72)
  float sc0[4], sh0[4];
#pragma unroll
  for (int k = 0; k < 4; ++k) { sc0[k] = lds_s0[k]; sh0[k] = lds_sh0[k]; }
  for (int e = 0; e < 32; ++e) {
    int flat = e * 256 + tid;
    int row = flat >> 6, col = flat & 63;
    float acc = lds_b0[col];
#pragma unroll
    for (int k = 0; k < 4; ++k)
      acc = fmaf(fmaf(lds_x[row * 4 + k], sc0[k], sh0[k]),
                 lds_W0[k * 64 + col], acc);
    float z = tanh_fast(acc);
    lds_y2[row * 72 + col] = f2bf(fmaf(lds_A1[col], z, lds_B1[col]));
  }
  __syncthreads();

  // phase B: store Y1, matmul2 for stats(Z2)
  const int wr = wave * 32;
  bfrag a2[2][2], bw[4][2];
#pragma unroll
  for (int mt = 0; mt < 2; ++mt)
#pragma unroll
    for (int kt = 0; kt < 2; ++kt) {
      a2[mt][kt] =
          *(const bfrag*)&lds_y2[(wr + mt * 16 + l15) * 72 + kt * 32 + q * 8];
      *(bfrag*)(Y + (r0 + wr + mt * 16 + l15) * 64 + kt * 32 + q * 8) =
          a2[mt][kt];
    }
#pragma unroll
  for (int nt = 0; nt < 4; ++nt)
#pragma unroll
    for (int kt = 0; kt < 2; ++kt)
      bw[nt][kt] = *(const bfrag*)(WTb + (nt * 16 + l15) * 64 + kt * 32 + q * 8);
  facc acc2[2][4];
#pragma unroll
  for (int mt = 0; mt < 2; ++mt)
#pragma unroll
    for (int nt = 0; nt < 4; ++nt) {
      float bias = lds_bb[nt * 16 + l15];
      acc2[mt][nt][0] = bias; acc2[mt][nt][1] = bias;
      acc2[mt][nt][2] = bias; acc2[mt][nt][3] = bias;
    }
#pragma unroll
  for (int mt = 0; mt < 2; ++mt)
#pragma unroll
    for (int nt = 0; nt < 4; ++nt)
#pragma unroll
      for (int kt = 0; kt < 2; ++kt)
        acc2[mt][nt] = __builtin_amdgcn_mfma_f32_16x16x32_bf16(
            a2[mt][kt], bw[nt][kt], acc2[mt][nt], 0, 0, 0);
#pragma unroll
  for (int nt = 0; nt < 4; ++nt) {
    float s = 0.f, ss = 0.f;
#pragma unroll
    for (int mt = 0; mt < 2; ++mt)
#pragma unroll
      for (int i = 0; i < 4; ++i) {
        float z = tanh_fast(acc2[mt][nt][i]);
        s += z;
        ss = fmaf(z, z, ss);
      }
    s += __shfl_xor(s, 16); s += __shfl_xor(s, 32);
    ss += __shfl_xor(ss, 16); ss += __shfl_xor(ss, 32);
    if (q == 0) {
      atomicAdd(&lds_st[nt * 16 + l15], s);
      atomicAdd(&lds_st[64 + nt * 16 + l15], ss);
    }
  }
  __syncthreads();
  if (tid < 128) atomicAdd(&s2[tid], lds_st[tid]);
}

// K_mid: recompute Z_a = tanh(Y@WTa+ba) (stats sa known), Ynew = BN(Z_a)+Y,
// write Ynew; matmul2 with WTb only for stats sb of Z_b.
__global__ __launch_bounds__(256) void k_mid(
    short* __restrict__ Y, const short* __restrict__ WTa,
    const float* __restrict__ ba, const float* __restrict__ ga,
    const float* __restrict__ bea, const float* __restrict__ sa,
    const short* __restrict__ WTb, const float* __restrict__ bb,
    float* __restrict__ sb) {
  __shared__ __align__(16) short lds_y[128 * 72];
  __shared__ __align__(16) short lds_y2[128 * 72];
  __shared__ float lds_A[64], lds_Bc[64], lds_ba[64], lds_bb[64];
  __shared__ float lds_st[128];

  const int tid = threadIdx.x;
  const int lane = tid & 63;
  const int wave = tid >> 6;
  const int l15 = lane & 15;
  const int q = lane >> 4;
  const size_t r0 = (size_t)blockIdx.x * 128;

#pragma unroll
  for (int it = 0; it < 4; ++it) {
    int chunk = it * 256 + tid;
    int row = chunk >> 3;
    int c8 = (chunk & 7) * 8;
    *(bfrag*)&lds_y[row * 72 + c8] = *(const bfrag*)(Y + (r0 + row) * 64 + c8);
  }
  if (tid < 128) lds_st[tid] = 0.f;
  if (tid < 64) {
    float mean = sa[tid] * INV_B;
    float var = fmaf(-mean, mean, sa[64 + tid] * INV_B);
    float rs = rsqrtf(var + EPS);
    float A = ga[tid] * rs;
    lds_A[tid] = A;
    lds_Bc[tid] = fmaf(-A, mean, bea[tid]);
    lds_ba[tid] = ba[tid];
    lds_bb[tid] = bb[tid];
  }
  __syncthreads();

  const int wr = wave * 32;
  // matmul1: recompute Z_a (bit-identical to producer: same bf16 in, same order)
  bfrag a1[2][2], bw[4][2];
#pragma unroll
  for (int mt = 0; mt < 2; ++mt)
#pragma unroll
    for (int kt = 0; kt < 2; ++kt)
      a1[mt][kt] =
          *(const bfrag*)&lds_y[(wr + mt * 16 + l15) * 72 + kt * 32 + q * 8];
#pragma unroll
  for (int nt = 0; nt < 4; ++nt)
#pragma unroll
    for (int kt = 0; kt < 2; ++kt)
      bw[nt][kt] = *(const bfrag*)(WTa + (nt * 16 + l15) * 64 + kt * 32 + q * 8);
  facc acc[2][4];
#pragma unroll
  for (int mt = 0; mt < 2; ++mt)
#pragma unroll
    for (int nt = 0; nt < 4; ++nt) {
      float bias = lds_ba[nt * 16 + l15];
      acc[mt][nt][0] = bias; acc[mt][nt][1] = bias;
      acc[mt][nt][2] = bias; acc[mt][nt][3] = bias;
    }
#pragma unroll
  for (int mt = 0; mt < 2; ++mt)
#pragma unroll
    for (int nt = 0; nt < 4; ++nt)
#pragma unroll
      for (int kt = 0; kt < 2; ++kt)
        acc[mt][nt] = __builtin_amdgcn_mfma_f32_16x16x32_bf16(
            a1[mt][kt], bw[nt][kt], acc[mt][nt], 0, 0, 0);

  // phase 3: BN + residual, C-layout -> lds_y2 (scalar LDS round-trip)
#pragma unroll
  for (int mt = 0; mt < 2; ++mt)
#pragma unroll
    for (int nt = 0; nt < 4; ++nt) {
      int c = nt * 16 + l15;
      float A = lds_A[c], Bc = lds_Bc[c];
#pragma unroll
      for (int i = 0; i < 4; ++i) {
        int rl = wr + mt * 16 + q * 4 + i;
        float z = tanh_fast(acc[mt][nt][i]);
        float yo = bf2f(lds_y[rl * 72 + c]);
        lds_y2[rl * 72 + c] = f2bf(fmaf(A, z, Bc) + yo);
      }
    }
  __syncthreads();

  // phase 4: store Ynew (from A-frag regs, coalesced), matmul2 for stats
  bfrag a2[2][2];
#pragma unroll
  for (int mt = 0; mt < 2; ++mt)
#pragma unroll
    for (int kt = 0; kt < 2; ++kt) {
      a2[mt][kt] =
          *(const bfrag*)&lds_y2[(wr + mt * 16 + l15) * 72 + kt * 32 + q * 8];
      *(bfrag*)(Y + (r0 + wr + mt * 16 + l15) * 64 + kt * 32 + q * 8) =
          a2[mt][kt];
    }
#pragma unroll
  for (int nt = 0; nt < 4; ++nt)
#pragma unroll
    for (int kt = 0; kt < 2; ++kt)
      bw[nt][kt] = *(const bfrag*)(WTb + (nt * 16 + l15) * 64 + kt * 32 + q * 8);
  facc acc2[2][4];
#pragma unroll
  for (int mt = 0; mt < 2; ++mt)
#pragma unroll
    for (int nt = 0; nt < 4; ++nt) {
      float bias = lds_bb[nt * 16 + l15];
      acc2[mt][nt][0] = bias; acc2[mt][nt][1] = bias;
      acc2[mt][nt][2] = bias; acc2[mt][nt][3] = bias;
    }
#pragma unroll
  for (int mt = 0; mt < 2; ++mt)
#pragma unroll
    for (int nt = 0; nt < 4; ++nt)
#pragma unroll
      for (int kt = 0; kt < 2; ++kt)
        acc2[mt][nt] = __builtin_amdgcn_mfma_f32_16x16x32_bf16(
            a2[mt][kt], bw[nt][kt], acc2[mt][nt], 0, 0, 0);
#pragma unroll
  for (int nt = 0; nt < 4; ++nt) {
    float s = 0.f, ss = 0.f;
#pragma unroll
    for (int mt = 0; mt < 2; ++mt)
#pragma unroll
      for (int i = 0; i < 4; ++i) {
        float z = tanh_fast(acc2[mt][nt][i]);
        s += z;
        ss = fmaf(z, z, ss);
      }
    s += __shfl_xor(s, 16); s += __shfl_xor(s, 32);
    ss += __shfl_xor(ss, 16); ss += __shfl_xor(ss, 32);
    if (q == 0) {
      atomicAdd(&lds_st[nt * 16 + l15], s);
      atomicAdd(&lds_st[64 + nt * 16 + l15], ss);
    }
  }
  __syncthreads();
  if (tid < 128) atomicAdd(&sb[tid], lds_st[tid]);
}

// K_last: recompute Z5, Y5 = BN(Z5)+Y4, out = Y5 @ Wout + bout
__global__ __launch_bounds__(256) void k_last(
    const short* __restrict__ Y, const short* __restrict__ WTa,
    const float* __restrict__ ba, const float* __restrict__ ga,
    const float* __restrict__ bea, const float* __restrict__ sa,
    const float* __restrict__ Wout, const float* __restrict__ bout,
    float* __restrict__ out) {
  __shared__ __align__(16) short lds_y[128 * 72];
  __shared__ __align__(16) short lds_y2[128 * 72];
  __shared__ float lds_A[64], lds_Bc[64], lds_ba[64];
  __shared__ float lds_wo[192];
  __shared__ float lds_bo[3];

  const int tid = threadIdx.x;
  const int lane = tid & 63;
  const int wave = tid >> 6;
  const int l15 = lane & 15;
  const int q = lane >> 4;
  const size_t r0 = (size_t)blockIdx.x * 128;

#pragma unroll
  for (int it = 0; it < 4; ++it) {
    int chunk = it * 256 + tid;
    int row = chunk >> 3;
    int c8 = (chunk & 7) * 8;
    *(bfrag*)&lds_y[row * 72 + c8] = *(const bfrag*)(Y + (r0 + row) * 64 + c8);
  }
  if (tid < 64) {
    float mean = sa[tid] * INV_B;
    float var = fmaf(-mean, mean, sa[64 + tid] * INV_B);
    float rs = rsqrtf(var + EPS);
    float A = ga[tid] * rs;
    lds_A[tid] = A;
    lds_Bc[tid] = fmaf(-A, mean, bea[tid]);
    lds_ba[tid] = ba[tid];
  }
  if (tid < 192) lds_wo[tid] = Wout[tid];
  if (tid < 3) lds_bo[tid] = bout[tid];
  __syncthreads();

  const int wr = wave * 32;
  bfrag a1[2][2], bw[4][2];
#pragma unroll
  for (int mt = 0; mt < 2; ++mt)
#pragma unroll
    for (int kt = 0; kt < 2; ++kt)
      a1[mt][kt] =
          *(const bfrag*)&lds_y[(wr + mt * 16 + l15) * 72 + kt * 32 + q * 8];
#pragma unroll
  for (int nt = 0; nt < 4; ++nt)
#pragma unroll
    for (int kt = 0; kt < 2; ++kt)
      bw[nt][kt] = *(const bfrag*)(WTa + (nt * 16 + l15) * 64 + kt * 32 + q * 8);
  facc acc[2][4];
#pragma unroll
  for (int mt = 0; mt < 2; ++mt)
#pragma unroll
    for (int nt = 0; nt < 4; ++nt) {
      float bias = lds_ba[nt * 16 + l15];
      acc[mt][nt][0] = bias; acc[mt][nt][1] = bias;
      acc[mt][nt][2] = bias; acc[mt][nt][3] = bias;
    }
#pragma unroll
  for (int mt = 0; mt < 2; ++mt)
#pragma unroll
    for (int nt = 0; nt < 4; ++nt)
#pragma unroll
      for (int kt = 0; kt < 2; ++kt)
        acc[mt][nt] = __builtin_amdgcn_mfma_f32_16x16x32_bf16(
            a1[mt][kt], bw[nt][kt], acc[mt][nt], 0, 0, 0);
#pragma unroll
  for (int mt = 0; mt < 2; ++mt)
#pragma unroll
    for (int nt = 0; nt < 4; ++nt) {
      int c = nt * 16 + l15;
      float A = lds_A[c], Bc = lds_Bc[c];
#pragma unroll
      for (int i = 0; i < 4; ++i) {
        int rl = wr + mt * 16 + q * 4 + i;
        float z = tanh_fast(acc[mt][nt][i]);
        float yo = bf2f(lds_y[rl * 72 + c]);
        lds_y2[rl * 72 + c] = f2bf(fmaf(A, z, Bc) + yo);
      }
    }
  __syncthreads();

  if (tid < 128) {
    float o0 = lds_bo[0], o1 = lds_bo[1], o2 = lds_bo[2];
#pragma unroll
    for (int jc = 0; jc < 8; ++jc) {
      bfrag v = *(const bfrag*)&lds_y2[tid * 72 + jc * 8];
#pragma unroll
      for (int j = 0; j < 8; ++j) {
        float f = bf2f(v[j]);
        int jj = jc * 8 + j;
        o0 = fmaf(f, lds_wo[jj * 3 + 0], o0);
        o1 = fmaf(f, lds_wo[jj * 3 + 1], o1);
        o2 = fmaf(f, lds_wo[jj * 3 + 2], o2);
      }
    }
    size_t ro = (r0 + tid) * 3;
    out[ro] = o0;
    out[ro + 1] = o1;
    out[ro + 2] = o2;
  }
}

extern "C" void kernel_launch(void* const* d_in, const int* in_sizes, int n_in,
                              void* d_out, int out_size, void* d_ws,
                              size_t ws_size, hipStream_t stream) {
  (void)in_sizes; (void)n_in; (void)out_size; (void)ws_size;
  const float* x = (const float*)d_in[0];
  const float* bn0g = (const float*)d_in[1];
  const float* bn0b = (const float*)d_in[2];
  const float* W0 = (const float*)d_in[3];
  const float* b0 = (const float*)d_in[4];
  const float* gamma0 = (const float*)d_in[5];
  const float* beta0 = (const float*)d_in[6];
  const float* Wh = (const float*)d_in[7];
  const float* bh = (const float*)d_in[8];
  const float* gh = (const float*)d_in[9];
  const float* beh = (const float*)d_in[10];
  const float* Wout = (const float*)d_in[11];
  const float* bout = (const float*)d_in[12];
  float* out = (float*)d_out;

  char* ws = (char*)d_ws;
  short* Y = (short*)ws;                       // 1M x 64 bf16 = 128 MB
  const size_t YB = (size_t)NROWS * 64 * 2;
  float* stats = (float*)(ws + YB);            // [Sx 8][S1..S5 128 each]
  float* Sx = stats;
  float* S1 = stats + 8;
  float* S2 = stats + 136;
  float* S3 = stats + 264;
  float* S4 = stats + 392;
  float* S5 = stats + 520;
  short* WT = (short*)(ws + YB + 4096);        // 4 x 64 x 64 bf16

  hipMemsetAsync(stats, 0, 648 * sizeof(float), stream);
  k_prep<<<64, 256, 0, stream>>>(Wh, WT);
  k_stats_x<<<1024, 256, 0, stream>>>(x, Sx);
  k_stats_z1<<<1024, 256, 0, stream>>>(x, bn0g, bn0b, W0, b0, Sx, S1);
  k_first<<<8192, 256, 0, stream>>>(x, bn0g, bn0b, W0, b0, gamma0, beta0, Sx,
                                    S1, WT, bh, S2, Y);
  k_mid<<<8192, 256, 0, stream>>>(Y, WT, bh, gh, beh, S2, WT + 4096, bh + 64,
                                  S3);
  k_mid<<<8192, 256, 0, stream>>>(Y, WT + 4096, bh + 64, gh + 64, beh + 64, S3,
                                  WT + 2 * 4096, bh + 128, S4);
  k_mid<<<8192, 256, 0, stream>>>(Y, WT + 2 * 4096, bh + 128, gh + 128,
                                  beh + 128, S4, WT + 3 * 4096, bh + 192, S5);
  k_last<<<8192, 256, 0, stream>>>(Y, WT + 3 * 4096, bh + 192, gh + 192,
                                   beh + 192, S5, Wout, bout, out);
}

// Round 2
// 568.559 us; speedup vs baseline: 4.4624x; 4.4624x over previous
//
#include <hip/hip_runtime.h>
#include <stdint.h>

// B = 1048576 rows, HID = 64. Residual MLP with training-mode BatchNorm.
// Recompute-fused layer kernels + bf16 activations (128 MB in d_ws).
// Round 2: stats via per-block partial rows + reduce kernels (NO global
// atomic contention), in-place LDS tile (20 KB -> 8 blocks/CU), rcp-based tanh.
// MFMA 16x16x32 bf16 layouts (verified gfx950 mappings):
//   A: row = lane&15, k = (lane>>4)*8 + j   (16B contiguous -> b128)
//   B: col = lane&15, k = (lane>>4)*8 + j   (load from W^T, row-major)
//   C/D: col = lane&15, row = (lane>>4)*4 + reg

#define NROWS 1048576
#define EPS 1e-5f
#define INV_B 9.5367431640625e-07f  // 1/2^20 exact
#define LOG2E2 2.885390081777927f   // 2*log2(e)

typedef __attribute__((ext_vector_type(8))) short bfrag;   // 8 bf16 = 4 VGPR
typedef __attribute__((ext_vector_type(4))) float facc;    // MFMA C/D
typedef __attribute__((ext_vector_type(4))) float f4v;

__device__ __forceinline__ float bf2f(short s) {
  union { unsigned u; float f; } v;
  v.u = ((unsigned)(unsigned short)s) << 16;
  return v.f;
}
__device__ __forceinline__ short f2bf(float f) {
  union { float f; unsigned u; } v;
  v.f = f;
  unsigned r = v.u + 0x7FFFu + ((v.u >> 16) & 1u);  // RNE
  return (short)(r >> 16);
}
// tanh = 1 - 2/(e^{2x}+1); v_exp + v_rcp, no divide, handles +-inf saturation
__device__ __forceinline__ float tanh_fast(float x) {
  float e = __builtin_amdgcn_exp2f(x * LOG2E2);
  return 1.f - 2.f * __builtin_amdgcn_rcpf(e + 1.f);
}

// ---------------- reduce: P[nb][W] -> atomicAdd into S[W] ----------------
template <int W>
__global__ __launch_bounds__(256) void k_reduce(const float* __restrict__ P,
                                                float* __restrict__ S,
                                                int rows_per_blk) {
  __shared__ float red[256];
  const int tid = threadIdx.x;
  const int col = tid % W;
  const int grp = tid / W;
  const int G = 256 / W;
  size_t r0 = (size_t)blockIdx.x * rows_per_blk;
  float s = 0.f;
  for (int r = grp; r < rows_per_blk; r += G) s += P[(r0 + r) * W + col];
  red[tid] = s;
  __syncthreads();
  if (tid < W) {
    float t = 0.f;
#pragma unroll 4
    for (int g = 0; g < G; ++g) t += red[g * W + tid];
    atomicAdd(&S[tid], t);
  }
}

// ---------------- small kernels ----------------

// stats of x (4 cols): per-block partial -> P[bid][8] (sum 4, sumsq 4)
__global__ __launch_bounds__(256) void k_stats_x(const float* __restrict__ x,
                                                 float* __restrict__ P) {
  __shared__ float red[4][8];
  const int tid = threadIdx.x;
  const int wave = tid >> 6;
  size_t base = (size_t)blockIdx.x * 1024 + tid;
  float s[4] = {0.f, 0.f, 0.f, 0.f}, q[4] = {0.f, 0.f, 0.f, 0.f};
#pragma unroll
  for (int it = 0; it < 4; ++it) {
    f4v v = *(const f4v*)(x + (base + (size_t)it * 256) * 4);
#pragma unroll
    for (int k = 0; k < 4; ++k) { s[k] += v[k]; q[k] = fmaf(v[k], v[k], q[k]); }
  }
#pragma unroll
  for (int off = 32; off > 0; off >>= 1) {
#pragma unroll
    for (int k = 0; k < 4; ++k) {
      s[k] += __shfl_xor(s[k], off);
      q[k] += __shfl_xor(q[k], off);
    }
  }
  if ((tid & 63) == 0) {
#pragma unroll
    for (int k = 0; k < 4; ++k) { red[wave][k] = s[k]; red[wave][4 + k] = q[k]; }
  }
  __syncthreads();
  if (tid < 8)
    P[blockIdx.x * 8 + tid] =
        red[0][tid] + red[1][tid] + red[2][tid] + red[3][tid];
}

// stats of Z1 = tanh(bn0(x) @ W0 + b0): wave handles 256 rows, lane = col;
// per-block partial -> P[bid][128]
__global__ __launch_bounds__(256) void k_stats_z1(
    const float* __restrict__ x, const float* __restrict__ bn0g,
    const float* __restrict__ bn0b, const float* __restrict__ W0,
    const float* __restrict__ b0, const float* __restrict__ sx,
    float* __restrict__ P) {
  __shared__ float red[2][4][64];
  const int tid = threadIdx.x;
  const int lane = tid & 63;
  const int wave = tid >> 6;
  int gw = blockIdx.x * 4 + wave;
  float sc[4], sh[4];
#pragma unroll
  for (int k = 0; k < 4; ++k) {
    float mean = sx[k] * INV_B;
    float var = fmaf(-mean, mean, sx[4 + k] * INV_B);
    float rs = rsqrtf(var + EPS);
    sc[k] = bn0g[k] * rs;
    sh[k] = fmaf(-sc[k], mean, bn0b[k]);
  }
  float w[4];
#pragma unroll
  for (int k = 0; k < 4; ++k) w[k] = W0[k * 64 + lane];
  float bj = b0[lane];
  float s = 0.f, q = 0.f;
  size_t r0 = (size_t)gw * 256;
  for (int r = 0; r < 256; ++r) {
    f4v xv = *(const f4v*)(x + (r0 + r) * 4);
    float acc = bj;
#pragma unroll
    for (int k = 0; k < 4; ++k)
      acc = fmaf(fmaf(xv[k], sc[k], sh[k]), w[k], acc);
    float z = tanh_fast(acc);
    s += z;
    q = fmaf(z, z, q);
  }
  red[0][wave][lane] = s;
  red[1][wave][lane] = q;
  __syncthreads();
  if (tid < 128) {
    int which = tid >> 6, c = tid & 63;
    P[blockIdx.x * 128 + tid] = red[which][0][c] + red[which][1][c] +
                                red[which][2][c] + red[which][3][c];
  }
}

// transpose W_hid (4 x 64 x 64) -> bf16 W^T, WT[l][c][k]
__global__ __launch_bounds__(256) void k_prep(const float* __restrict__ Wh,
                                              short* __restrict__ WT) {
  int idx = blockIdx.x * 256 + threadIdx.x;  // 16384 total
  int l = idx >> 12, rem = idx & 4095, k = rem >> 6, c = rem & 63;
  WT[l * 4096 + c * 64 + k] = f2bf(Wh[l * 4096 + k * 64 + c]);
}

// ---------------- big fused kernels: 128 rows/block, 4 waves of 32 rows ----

// K_first: Y1 = BN(tanh(bn0(x)@W0+b0)) (no skip), write Y1 bf16,
// partial stats of Z2 = tanh(Y1 @ W_hid0 + b_hid0) -> P[bid][128]
__global__ __launch_bounds__(256) void k_first(
    const float* __restrict__ x, const float* __restrict__ bn0g,
    const float* __restrict__ bn0b, const float* __restrict__ W0,
    const float* __restrict__ b0, const float* __restrict__ gamma0,
    const float* __restrict__ beta0, const float* __restrict__ sx,
    const float* __restrict__ s1, const short* __restrict__ WTb,
    const float* __restrict__ bb, float* __restrict__ P,
    short* __restrict__ Y) {
  __shared__ __align__(16) float lds_x[128 * 4];
  __shared__ float lds_W0[256];
  __shared__ float lds_b0[64], lds_A1[64], lds_B1[64], lds_bb[64];
  __shared__ float lds_s0[4], lds_sh0[4];
  __shared__ __align__(16) short lds_y[128 * 72];
  __shared__ float lds_st[128];

  const int tid = threadIdx.x;
  const int lane = tid & 63;
  const int wave = tid >> 6;
  const int l15 = lane & 15;
  const int q = lane >> 4;
  const size_t r0 = (size_t)blockIdx.x * 128;

  if (tid < 128) {
    *(f4v*)(lds_x + tid * 4) = *(const f4v*)(x + (r0 + tid) * 4);
    lds_st[tid] = 0.f;
  }
  lds_W0[tid] = W0[tid];
  if (tid < 64) {
    lds_b0[tid] = b0[tid];
    float mean = s1[tid] * INV_B;
    float var = fmaf(-mean, mean, s1[64 + tid] * INV_B);
    float rs = rsqrtf(var + EPS);
    float A = gamma0[tid] * rs;
    lds_A1[tid] = A;
    lds_B1[tid] = fmaf(-A, mean, beta0[tid]);
    lds_bb[tid] = bb[tid];
  }
  if (tid < 4) {
    float mean = sx[tid] * INV_B;
    float var = fmaf(-mean, mean, sx[4 + tid] * INV_B);
    float rs = rsqrtf(var + EPS);
    float sc = bn0g[tid] * rs;
    lds_s0[tid] = sc;
    lds_sh0[tid] = fmaf(-sc, mean, bn0b[tid]);
  }
  __syncthreads();

  const int wr = wave * 32;
  // phase A: Y1 tile (wave-private rows -> no barrier needed before phase B)
  float sc0[4], sh0[4];
#pragma unroll
  for (int k = 0; k < 4; ++k) { sc0[k] = lds_s0[k]; sh0[k] = lds_sh0[k]; }
  for (int e = 0; e < 32; ++e) {
    int row = wr + e;
    float acc = lds_b0[lane];
#pragma unroll
    for (int k = 0; k < 4; ++k)
      acc = fmaf(fmaf(lds_x[row * 4 + k], sc0[k], sh0[k]),
                 lds_W0[k * 64 + lane], acc);
    float z = tanh_fast(acc);
    lds_y[row * 72 + lane] = f2bf(fmaf(lds_A1[lane], z, lds_B1[lane]));
  }

  // phase B: store Y1, matmul2 for stats(Z2)
  bfrag a2[2][2], bw[4][2];
#pragma unroll
  for (int mt = 0; mt < 2; ++mt)
#pragma unroll
    for (int kt = 0; kt < 2; ++kt) {
      a2[mt][kt] =
          *(const bfrag*)&lds_y[(wr + mt * 16 + l15) * 72 + kt * 32 + q * 8];
      *(bfrag*)(Y + (r0 + wr + mt * 16 + l15) * 64 + kt * 32 + q * 8) =
          a2[mt][kt];
    }
#pragma unroll
  for (int nt = 0; nt < 4; ++nt)
#pragma unroll
    for (int kt = 0; kt < 2; ++kt)
      bw[nt][kt] = *(const bfrag*)(WTb + (nt * 16 + l15) * 64 + kt * 32 + q * 8);
  facc acc2[2][4];
#pragma unroll
  for (int mt = 0; mt < 2; ++mt)
#pragma unroll
    for (int nt = 0; nt < 4; ++nt) {
      float bias = lds_bb[nt * 16 + l15];
      acc2[mt][nt][0] = bias; acc2[mt][nt][1] = bias;
      acc2[mt][nt][2] = bias; acc2[mt][nt][3] = bias;
    }
#pragma unroll
  for (int mt = 0; mt < 2; ++mt)
#pragma unroll
    for (int nt = 0; nt < 4; ++nt)
#pragma unroll
      for (int kt = 0; kt < 2; ++kt)
        acc2[mt][nt] = __builtin_amdgcn_mfma_f32_16x16x32_bf16(
            a2[mt][kt], bw[nt][kt], acc2[mt][nt], 0, 0, 0);
#pragma unroll
  for (int nt = 0; nt < 4; ++nt) {
    float s = 0.f, ss = 0.f;
#pragma unroll
    for (int mt = 0; mt < 2; ++mt)
#pragma unroll
      for (int i = 0; i < 4; ++i) {
        float z = tanh_fast(acc2[mt][nt][i]);
        s += z;
        ss = fmaf(z, z, ss);
      }
    s += __shfl_xor(s, 16); s += __shfl_xor(s, 32);
    ss += __shfl_xor(ss, 16); ss += __shfl_xor(ss, 32);
    if (q == 0) {
      atomicAdd(&lds_st[nt * 16 + l15], s);
      atomicAdd(&lds_st[64 + nt * 16 + l15], ss);
    }
  }
  __syncthreads();
  if (tid < 128) P[(size_t)blockIdx.x * 128 + tid] = lds_st[tid];
}

// K_mid: recompute Z_a = tanh(Y@WTa+ba) (stats sa known), Ynew = BN(Z_a)+Y
// (in-place LDS tile), write Ynew; matmul2 with WTb for partial stats of Z_b.
__global__ __launch_bounds__(256) void k_mid(
    short* __restrict__ Y, const short* __restrict__ WTa,
    const float* __restrict__ ba, const float* __restrict__ ga,
    const float* __restrict__ bea, const float* __restrict__ sa,
    const short* __restrict__ WTb, const float* __restrict__ bb,
    float* __restrict__ P) {
  __shared__ __align__(16) short lds_y[128 * 72];
  __shared__ float lds_A[64], lds_Bc[64], lds_ba[64], lds_bb[64];
  __shared__ float lds_st[128];

  const int tid = threadIdx.x;
  const int lane = tid & 63;
  const int wave = tid >> 6;
  const int l15 = lane & 15;
  const int q = lane >> 4;
  const size_t r0 = (size_t)blockIdx.x * 128;

#pragma unroll
  for (int it = 0; it < 4; ++it) {
    int chunk = it * 256 + tid;
    int row = chunk >> 3;
    int c8 = (chunk & 7) * 8;
    *(bfrag*)&lds_y[row * 72 + c8] = *(const bfrag*)(Y + (r0 + row) * 64 + c8);
  }
  if (tid < 128) lds_st[tid] = 0.f;
  if (tid < 64) {
    float mean = sa[tid] * INV_B;
    float var = fmaf(-mean, mean, sa[64 + tid] * INV_B);
    float rs = rsqrtf(var + EPS);
    float A = ga[tid] * rs;
    lds_A[tid] = A;
    lds_Bc[tid] = fmaf(-A, mean, bea[tid]);
    lds_ba[tid] = ba[tid];
    lds_bb[tid] = bb[tid];
  }
  __syncthreads();

  const int wr = wave * 32;
  // matmul1: recompute Z_a (deterministic: same bf16 in, same op order as producer)
  bfrag a1[2][2], bw[4][2];
#pragma unroll
  for (int mt = 0; mt < 2; ++mt)
#pragma unroll
    for (int kt = 0; kt < 2; ++kt)
      a1[mt][kt] =
          *(const bfrag*)&lds_y[(wr + mt * 16 + l15) * 72 + kt * 32 + q * 8];
#pragma unroll
  for (int nt = 0; nt < 4; ++nt)
#pragma unroll
    for (int kt = 0; kt < 2; ++kt)
      bw[nt][kt] = *(const bfrag*)(WTa + (nt * 16 + l15) * 64 + kt * 32 + q * 8);
  facc acc[2][4];
#pragma unroll
  for (int mt = 0; mt < 2; ++mt)
#pragma unroll
    for (int nt = 0; nt < 4; ++nt) {
      float bias = lds_ba[nt * 16 + l15];
      acc[mt][nt][0] = bias; acc[mt][nt][1] = bias;
      acc[mt][nt][2] = bias; acc[mt][nt][3] = bias;
    }
#pragma unroll
  for (int mt = 0; mt < 2; ++mt)
#pragma unroll
    for (int nt = 0; nt < 4; ++nt)
#pragma unroll
      for (int kt = 0; kt < 2; ++kt)
        acc[mt][nt] = __builtin_amdgcn_mfma_f32_16x16x32_bf16(
            a1[mt][kt], bw[nt][kt], acc[mt][nt], 0, 0, 0);

  // phase 3: BN + residual, in-place (each element read+written by its owner
  // lane only; all rows wave-private -> no barrier needed)
#pragma unroll
  for (int mt = 0; mt < 2; ++mt)
#pragma unroll
    for (int nt = 0; nt < 4; ++nt) {
      int c = nt * 16 + l15;
      float A = lds_A[c], Bc = lds_Bc[c];
#pragma unroll
      for (int i = 0; i < 4; ++i) {
        int rl = wr + mt * 16 + q * 4 + i;
        float z = tanh_fast(acc[mt][nt][i]);
        float yo = bf2f(lds_y[rl * 72 + c]);
        lds_y[rl * 72 + c] = f2bf(fmaf(A, z, Bc) + yo);
      }
    }

  // phase 4: store Ynew (wave-private rows, coalesced b128), matmul2 for stats
  bfrag a2[2][2];
#pragma unroll
  for (int mt = 0; mt < 2; ++mt)
#pragma unroll
    for (int kt = 0; kt < 2; ++kt) {
      a2[mt][kt] =
          *(const bfrag*)&lds_y[(wr + mt * 16 + l15) * 72 + kt * 32 + q * 8];
      *(bfrag*)(Y + (r0 + wr + mt * 16 + l15) * 64 + kt * 32 + q * 8) =
          a2[mt][kt];
    }
#pragma unroll
  for (int nt = 0; nt < 4; ++nt)
#pragma unroll
    for (int kt = 0; kt < 2; ++kt)
      bw[nt][kt] = *(const bfrag*)(WTb + (nt * 16 + l15) * 64 + kt * 32 + q * 8);
  facc acc2[2][4];
#pragma unroll
  for (int mt = 0; mt < 2; ++mt)
#pragma unroll
    for (int nt = 0; nt < 4; ++nt) {
      float bias = lds_bb[nt * 16 + l15];
      acc2[mt][nt][0] = bias; acc2[mt][nt][1] = bias;
      acc2[mt][nt][2] = bias; acc2[mt][nt][3] = bias;
    }
#pragma unroll
  for (int mt = 0; mt < 2; ++mt)
#pragma unroll
    for (int nt = 0; nt < 4; ++nt)
#pragma unroll
      for (int kt = 0; kt < 2; ++kt)
        acc2[mt][nt] = __builtin_amdgcn_mfma_f32_16x16x32_bf16(
            a2[mt][kt], bw[nt][kt], acc2[mt][nt], 0, 0, 0);
#pragma unroll
  for (int nt = 0; nt < 4; ++nt) {
    float s = 0.f, ss = 0.f;
#pragma unroll
    for (int mt = 0; mt < 2; ++mt)
#pragma unroll
      for (int i = 0; i < 4; ++i) {
        float z = tanh_fast(acc2[mt][nt][i]);
        s += z;
        ss = fmaf(z, z, ss);
      }
    s += __shfl_xor(s, 16); s += __shfl_xor(s, 32);
    ss += __shfl_xor(ss, 16); ss += __shfl_xor(ss, 32);
    if (q == 0) {
      atomicAdd(&lds_st[nt * 16 + l15], s);
      atomicAdd(&lds_st[64 + nt * 16 + l15], ss);
    }
  }
  __syncthreads();
  if (tid < 128) P[(size_t)blockIdx.x * 128 + tid] = lds_st[tid];
}

// K_last: recompute Z5, Y5 = BN(Z5)+Y4 (in-place), out = Y5 @ Wout + bout
__global__ __launch_bounds__(256) void k_last(
    const short* __restrict__ Y, const short* __restrict__ WTa,
    const float* __restrict__ ba, const float* __restrict__ ga,
    const float* __restrict__ bea, const float* __restrict__ sa,
    const float* __restrict__ Wout, const float* __restrict__ bout,
    float* __restrict__ out) {
  __shared__ __align__(16) short lds_y[128 * 72];
  __shared__ float lds_A[64], lds_Bc[64], lds_ba[64];
  __shared__ float lds_wo[192];
  __shared__ float lds_bo[3];

  const int tid = threadIdx.x;
  const int lane = tid & 63;
  const int wave = tid >> 6;
  const int l15 = lane & 15;
  const int q = lane >> 4;
  const size_t r0 = (size_t)blockIdx.x * 128;

#pragma unroll
  for (int it = 0; it < 4; ++it) {
    int chunk = it * 256 + tid;
    int row = chunk >> 3;
    int c8 = (chunk & 7) * 8;
    *(bfrag*)&lds_y[row * 72 + c8] = *(const bfrag*)(Y + (r0 + row) * 64 + c8);
  }
  if (tid < 64) {
    float mean = sa[tid] * INV_B;
    float var = fmaf(-mean, mean, sa[64 + tid] * INV_B);
    float rs = rsqrtf(var + EPS);
    float A = ga[tid] * rs;
    lds_A[tid] = A;
    lds_Bc[tid] = fmaf(-A, mean, bea[tid]);
    lds_ba[tid] = ba[tid];
  }
  if (tid < 192) lds_wo[tid] = Wout[tid];
  if (tid < 3) lds_bo[tid] = bout[tid];
  __syncthreads();

  const int wr = wave * 32;
  bfrag a1[2][2], bw[4][2];
#pragma unroll
  for (int mt = 0; mt < 2; ++mt)
#pragma unroll
    for (int kt = 0; kt < 2; ++kt)
      a1[mt][kt] =
          *(const bfrag*)&lds_y[(wr + mt * 16 + l15) * 72 + kt * 32 + q * 8];
#pragma unroll
  for (int nt = 0; nt < 4; ++nt)
#pragma unroll
    for (int kt = 0; kt < 2; ++kt)
      bw[nt][kt] = *(const bfrag*)(WTa + (nt * 16 + l15) * 64 + kt * 32 + q * 8);
  facc acc[2][4];
#pragma unroll
  for (int mt = 0; mt < 2; ++mt)
#pragma unroll
    for (int nt = 0; nt < 4; ++nt) {
      float bias = lds_ba[nt * 16 + l15];
      acc[mt][nt][0] = bias; acc[mt][nt][1] = bias;
      acc[mt][nt][2] = bias; acc[mt][nt][3] = bias;
    }
#pragma unroll
  for (int mt = 0; mt < 2; ++mt)
#pragma unroll
    for (int nt = 0; nt < 4; ++nt)
#pragma unroll
      for (int kt = 0; kt < 2; ++kt)
        acc[mt][nt] = __builtin_amdgcn_mfma_f32_16x16x32_bf16(
            a1[mt][kt], bw[nt][kt], acc[mt][nt], 0, 0, 0);
#pragma unroll
  for (int mt = 0; mt < 2; ++mt)
#pragma unroll
    for (int nt = 0; nt < 4; ++nt) {
      int c = nt * 16 + l15;
      float A = lds_A[c], Bc = lds_Bc[c];
#pragma unroll
      for (int i = 0; i < 4; ++i) {
        int rl = wr + mt * 16 + q * 4 + i;
        float z = tanh_fast(acc[mt][nt][i]);
        float yo = bf2f(lds_y[rl * 72 + c]);
        lds_y[rl * 72 + c] = f2bf(fmaf(A, z, Bc) + yo);
      }
    }
  __syncthreads();  // epilogue reads rows across waves

  if (tid < 128) {
    float o0 = lds_bo[0], o1 = lds_bo[1], o2 = lds_bo[2];
#pragma unroll
    for (int jc = 0; jc < 8; ++jc) {
      bfrag v = *(const bfrag*)&lds_y[tid * 72 + jc * 8];
#pragma unroll
      for (int j = 0; j < 8; ++j) {
        float f = bf2f(v[j]);
        int jj = jc * 8 + j;
        o0 = fmaf(f, lds_wo[jj * 3 + 0], o0);
        o1 = fmaf(f, lds_wo[jj * 3 + 1], o1);
        o2 = fmaf(f, lds_wo[jj * 3 + 2], o2);
      }
    }
    size_t ro = (r0 + tid) * 3;
    out[ro] = o0;
    out[ro + 1] = o1;
    out[ro + 2] = o2;
  }
}

extern "C" void kernel_launch(void* const* d_in, const int* in_sizes, int n_in,
                              void* d_out, int out_size, void* d_ws,
                              size_t ws_size, hipStream_t stream) {
  (void)in_sizes; (void)n_in; (void)out_size; (void)ws_size;
  const float* x = (const float*)d_in[0];
  const float* bn0g = (const float*)d_in[1];
  const float* bn0b = (const float*)d_in[2];
  const float* W0 = (const float*)d_in[3];
  const float* b0 = (const float*)d_in[4];
  const float* gamma0 = (const float*)d_in[5];
  const float* beta0 = (const float*)d_in[6];
  const float* Wh = (const float*)d_in[7];
  const float* bh = (const float*)d_in[8];
  const float* gh = (const float*)d_in[9];
  const float* beh = (const float*)d_in[10];
  const float* Wout = (const float*)d_in[11];
  const float* bout = (const float*)d_in[12];
  float* out = (float*)d_out;

  char* ws = (char*)d_ws;
  short* Y = (short*)ws;                       // 1M x 64 bf16 = 128 MB
  const size_t YB = (size_t)NROWS * 64 * 2;
  float* stats = (float*)(ws + YB);            // [Sx 8][S1..S5 128 each]
  float* Sx = stats;
  float* S1 = stats + 8;
  float* S2 = stats + 136;
  float* S3 = stats + 264;
  float* S4 = stats + 392;
  float* S5 = stats + 520;
  short* WT = (short*)(ws + YB + 4096);        // 4 x 64 x 64 bf16 = 32 KB
  float* P = (float*)(ws + YB + 4096 + 32768); // partials: up to 8192x128 f32 = 4 MB

  hipMemsetAsync(stats, 0, 648 * sizeof(float), stream);
  k_prep<<<64, 256, 0, stream>>>(Wh, WT);
  k_stats_x<<<1024, 256, 0, stream>>>(x, P);
  k_reduce<8><<<8, 256, 0, stream>>>(P, Sx, 128);
  k_stats_z1<<<1024, 256, 0, stream>>>(x, bn0g, bn0b, W0, b0, Sx, P);
  k_reduce<128><<<8, 256, 0, stream>>>(P, S1, 128);
  k_first<<<8192, 256, 0, stream>>>(x, bn0g, bn0b, W0, b0, gamma0, beta0, Sx,
                                    S1, WT, bh, P, Y);
  k_reduce<128><<<64, 256, 0, stream>>>(P, S2, 128);
  k_mid<<<8192, 256, 0, stream>>>(Y, WT, bh, gh, beh, S2, WT + 4096, bh + 64,
                                  P);
  k_reduce<128><<<64, 256, 0, stream>>>(P, S3, 128);
  k_mid<<<8192, 256, 0, stream>>>(Y, WT + 4096, bh + 64, gh + 64, beh + 64, S3,
                                  WT + 2 * 4096, bh + 128, P);
  k_reduce<128><<<64, 256, 0, stream>>>(P, S4, 128);
  k_mid<<<8192, 256, 0, stream>>>(Y, WT + 2 * 4096, bh + 128, gh + 128,
                                  beh + 128, S4, WT + 3 * 4096, bh + 192, P);
  k_reduce<128><<<64, 256, 0, stream>>>(P, S5, 128);
  k_last<<<8192, 256, 0, stream>>>(Y, WT + 3 * 4096, bh + 192, gh + 192,
                                   beh + 192, S5, Wout, bout, out);
}